// Round 5
// baseline (164.796 us; speedup 1.0000x reference)
//
#include <hip/hip_runtime.h>
#include <hip/hip_fp16.h>

// BuildK: per-pixel K=48 neighbor softmax of -sqrt(mean((u_j - u_nbr)^2) + eps)
// R5: keep R4's quad-cooperative gather shape (1 instr = 16 neighbors x 64 B
// contiguous segments) but process TWO pixels per wave with all 8 VMEM gathers
// (6 neighbor + 2 own) issued before any compute -> ~2x outstanding requests
// per wave (latency/MLP hypothesis). Also: softmax max-subtract removed —
// D = -sqrt(msd+eps) is in [-10, 0] so exp(D) is in [4.5e-5, 1]; no
// overflow/underflow possible; saves one serialized shfl-reduce chain/pixel.

#define EPS 1e-9f

typedef _Float16 h2 __attribute__((ext_vector_type(2)));
union V16 { uint4 u; h2 h[4]; };

__global__ __launch_bounds__(256) void transpose_half_kernel(
    const float* __restrict__ in, _Float16* __restrict__ UU, int N) {
  const int p = blockIdx.x * 256 + threadIdx.x;
  if (p >= N) return;
  __half h[32];
#pragma unroll
  for (int f = 0; f < 32; ++f) h[f] = __float2half_rn(in[(size_t)f * N + p]);
  uint4* dst = (uint4*)(UU + (size_t)p * 32);
#pragma unroll
  for (int r = 0; r < 4; ++r) {
    __half2 a = __halves2half2(h[8 * r + 0], h[8 * r + 1]);
    __half2 b = __halves2half2(h[8 * r + 2], h[8 * r + 3]);
    __half2 c = __halves2half2(h[8 * r + 4], h[8 * r + 5]);
    __half2 d = __halves2half2(h[8 * r + 6], h[8 * r + 7]);
    dst[r] = make_uint4(*(unsigned*)&a, *(unsigned*)&b, *(unsigned*)&c, *(unsigned*)&d);
  }
}

__device__ __forceinline__ float dot2acc(h2 d, float s) {
#if __has_builtin(__builtin_amdgcn_fdot2)
  return __builtin_amdgcn_fdot2(d, d, s, false);
#else
  float x = (float)d.x, y = (float)d.y;
  return s + x * x + y * y;
#endif
}

__global__ __launch_bounds__(256) void dist_softmax_kernel(
    const _Float16* __restrict__ UU, const int* __restrict__ idx,
    float* __restrict__ out, int J) {
  const int wave = blockIdx.x * 4 + (threadIdx.x >> 6);
  const int lane = threadIdx.x & 63;
  const int jA = wave * 2;      // J is even; jB valid whenever jA is
  const int jB = jA + 1;
  if (jA >= J) return;
  const int quad = lane >> 2;   // neighbor slot within a pass (0..15)
  const int q = lane & 3;       // 16-B chunk within the 64-B vector

  // neighbor indices for both pixels (quad-redundant dword reads, 64 B/instr)
  const int* iA = idx + (size_t)jA * 48;
  const int* iB = idx + (size_t)jB * 48;
  const int nA0 = iA[quad], nA1 = iA[16 + quad], nA2 = iA[32 + quad];
  const int nB0 = iB[quad], nB1 = iB[16 + quad], nB2 = iB[32 + quad];

  // issue all 8 dwordx4 loads before any compute: 2 own + 6 quad-cooperative
  // gathers (each instr covers 16 neighbors as contiguous 64-B segments)
  V16 aA, aB, bA0, bA1, bA2, bB0, bB1, bB2;
  aA.u = *(const uint4*)(UU + (size_t)jA * 32 + q * 8);
  aB.u = *(const uint4*)(UU + (size_t)jB * 32 + q * 8);
  bA0.u = *(const uint4*)(UU + (size_t)nA0 * 32 + q * 8);
  bA1.u = *(const uint4*)(UU + (size_t)nA1 * 32 + q * 8);
  bA2.u = *(const uint4*)(UU + (size_t)nA2 * 32 + q * 8);
  bB0.u = *(const uint4*)(UU + (size_t)nB0 * 32 + q * 8);
  bB1.u = *(const uint4*)(UU + (size_t)nB1 * 32 + q * 8);
  bB2.u = *(const uint4*)(UU + (size_t)nB2 * 32 + q * 8);

  float sA0 = 0.f, sA1 = 0.f, sA2 = 0.f;
  float sB0 = 0.f, sB1 = 0.f, sB2 = 0.f;
#pragma unroll
  for (int i = 0; i < 4; ++i) {
    const h2 avA = aA.h[i];
    const h2 avB = aB.h[i];
    sA0 = dot2acc(avA - bA0.h[i], sA0);
    sA1 = dot2acc(avA - bA1.h[i], sA1);
    sA2 = dot2acc(avA - bA2.h[i], sA2);
    sB0 = dot2acc(avB - bB0.h[i], sB0);
    sB1 = dot2acc(avB - bB1.h[i], sB1);
    sB2 = dot2acc(avB - bB2.h[i], sB2);
  }
  // reduce 8-feature partials across the 4 chunks of the quad
  sA0 += __shfl_xor(sA0, 1); sA0 += __shfl_xor(sA0, 2);
  sA1 += __shfl_xor(sA1, 1); sA1 += __shfl_xor(sA1, 2);
  sA2 += __shfl_xor(sA2, 1); sA2 += __shfl_xor(sA2, 2);
  sB0 += __shfl_xor(sB0, 1); sB0 += __shfl_xor(sB0, 2);
  sB1 += __shfl_xor(sB1, 1); sB1 += __shfl_xor(sB1, 2);
  sB2 += __shfl_xor(sB2, 1); sB2 += __shfl_xor(sB2, 2);

  // no max-subtract: D in [-10, 0] -> exp(D) in [4.5e-5, 1], always safe
  const float eA0 = __expf(-sqrtf(sA0 * (1.0f / 32.0f) + EPS));
  const float eA1 = __expf(-sqrtf(sA1 * (1.0f / 32.0f) + EPS));
  const float eA2 = __expf(-sqrtf(sA2 * (1.0f / 32.0f) + EPS));
  const float eB0 = __expf(-sqrtf(sB0 * (1.0f / 32.0f) + EPS));
  const float eB1 = __expf(-sqrtf(sB1 * (1.0f / 32.0f) + EPS));
  const float eB2 = __expf(-sqrtf(sB2 * (1.0f / 32.0f) + EPS));

  float tA = eA0 + eA1 + eA2;
  float tB = eB0 + eB1 + eB2;
#pragma unroll
  for (int off = 4; off < 64; off <<= 1) {
    tA += __shfl_xor(tA, off);
    tB += __shfl_xor(tB, off);
  }
  const float invA = 1.0f / tA;
  const float invB = 1.0f / tB;

  // lanes with q==0 write their quad's 3 weights per pixel
  if (q == 0) {
    float* oA = out + (size_t)jA * 48;
    float* oB = out + (size_t)jB * 48;
    oA[quad] = eA0 * invA;
    oA[16 + quad] = eA1 * invA;
    oA[32 + quad] = eA2 * invA;
    oB[quad] = eB0 * invB;
    oB[16 + quad] = eB1 * invB;
    oB[32 + quad] = eB2 * invB;
  }
}

extern "C" void kernel_launch(void* const* d_in, const int* in_sizes, int n_in,
                              void* d_out, int out_size, void* d_ws, size_t ws_size,
                              hipStream_t stream) {
  const float* in1 = (const float*)d_in[0];
  const int* idx = (const int*)d_in[1];  // harness delivers integer inputs as int32
  float* out = (float*)d_out;
  _Float16* UU = (_Float16*)d_ws;        // N*32 halfs = 9.4 MB scratch

  const int N = in_sizes[0] / 32;        // 147456
  const int J = in_sizes[1] / 48;        // 147456

  transpose_half_kernel<<<(N + 255) / 256, 256, 0, stream>>>(in1, UU, N);

  // two pixels per wave, 4 waves per block -> 8 pixels per block
  dist_softmax_kernel<<<(J + 7) / 8, 256, 0, stream>>>(UU, idx, out, J);
}